// Round 6
// baseline (2078.496 us; speedup 1.0000x reference)
//
#include <hip/hip_runtime.h>

#define NN 50000
#define EE 800000
#define GG 512
#define NCH 196   // ceil(NN/256)

typedef __attribute__((ext_vector_type(8))) short bf8_t;
typedef __attribute__((ext_vector_type(4))) float f4_t;

__device__ __forceinline__ short bf16r(float f) {
    unsigned u = __builtin_bit_cast(unsigned, f);
    u += 0x7fffu + ((u >> 16) & 1u);   // RNE
    return (short)(u >> 16);
}

struct Params {
    const float* x; const int* srcI; const int* dstI; const int* batch; const float* noise;
    const float *W1_0, *b1_0, *W2_0, *b2_0, *W1_r, *b1_r, *W2_r, *b2_r, *bn_g, *bn_b;
    const float *Wq, *Wk, *Wv, *Wih, *Whh, *bih, *bhh;
    const float *nmW, *nmb, *nlW, *nlb, *gmW, *gmb, *glW, *glb, *pj_g, *pj_b;
    float *A, *B, *C, *D, *slots, *gpre1, *gpre2, *attn, *stats;
    int *segst, *rowst, *cursor, *csum, *bofs, *bar, *csr;
    float *o_nmu, *o_nlv, *o_gmu, *o_glv;
};

// ---------------- hierarchical device-scope grid barrier ----------------
// bar[0..23] = group counters, bar[24] = root counter, bar[25] = generation.
// All zeroed by binit_k before mega_k each call (ws is poisoned between).

__global__ void binit_k(int* bar) { if (threadIdx.x < 32) bar[threadIdx.x] = 0; }

__device__ void gbar(int* bar, int target) {
    __syncthreads();
    if (threadIdx.x == 0) {
        const int nb = (int)gridDim.x;
        int grp = blockIdx.x >> 5;
        int gsz = min(32, nb - (grp << 5));
        bool last = false;
        if (__hip_atomic_fetch_add(&bar[grp], 1, __ATOMIC_ACQ_REL, __HIP_MEMORY_SCOPE_AGENT) == gsz - 1) {
            __hip_atomic_store(&bar[grp], 0, __ATOMIC_RELAXED, __HIP_MEMORY_SCOPE_AGENT);
            int ng = (nb + 31) >> 5;
            if (__hip_atomic_fetch_add(&bar[24], 1, __ATOMIC_ACQ_REL, __HIP_MEMORY_SCOPE_AGENT) == ng - 1) {
                __hip_atomic_store(&bar[24], 0, __ATOMIC_RELAXED, __HIP_MEMORY_SCOPE_AGENT);
                __hip_atomic_store(&bar[25], target, __ATOMIC_RELEASE, __HIP_MEMORY_SCOPE_AGENT);
                last = true;
            }
        }
        if (!last) {
            while (__hip_atomic_load(&bar[25], __ATOMIC_RELAXED, __HIP_MEMORY_SCOPE_AGENT) < target)
                __builtin_amdgcn_s_sleep(8);
            (void)__hip_atomic_load(&bar[25], __ATOMIC_ACQUIRE, __HIP_MEMORY_SCOPE_AGENT);
        }
    }
    __syncthreads();
}

// ---------------- per-lane stats reduce (over 16 row-lanes) + atomic ----------------

__device__ __forceinline__ void stat_red(f4_t a, int cb, int l15, float* gs) {
    f4_t s = a, q;
    q[0] = a[0]*a[0]; q[1] = a[1]*a[1]; q[2] = a[2]*a[2]; q[3] = a[3]*a[3];
#pragma unroll
    for (int o = 1; o < 16; o <<= 1) {
        s[0] += __shfl_xor(s[0], o); s[1] += __shfl_xor(s[1], o);
        s[2] += __shfl_xor(s[2], o); s[3] += __shfl_xor(s[3], o);
        q[0] += __shfl_xor(q[0], o); q[1] += __shfl_xor(q[1], o);
        q[2] += __shfl_xor(q[2], o); q[3] += __shfl_xor(q[3], o);
    }
    if (l15 == 0) {
        atomicAdd(&gs[cb+0], s[0]); atomicAdd(&gs[cb+1], s[1]);
        atomicAdd(&gs[cb+2], s[2]); atomicAdd(&gs[cb+3], s[3]);
        atomicAdd(&gs[64+cb+0], q[0]); atomicAdd(&gs[64+cb+1], q[1]);
        atomicAdd(&gs[64+cb+2], q[2]); atomicAdd(&gs[64+cb+3], q[3]);
    }
}

// ---------------- MFMA GEMM phase: out[rows x 64] = act(T(in)[rows x K] @ W + b) ----------------
// W staged to LDS transposed (bf16, pad 8) -> conflict-free ds_read_b128 A-fragments.
// Operand roles: A = W^T (m=outcol), B = activations (n=row) -> lane's C regs are 4
// consecutive output cols -> float4 stores.

template<int K, bool BIAS, bool RELU, bool STATS, bool BNIN, bool DUAL>
__device__ void gemm_phase(char* smem, const float* __restrict__ in,
    const float* __restrict__ W, const float* __restrict__ Wb,
    const float* __restrict__ bias, const float* __restrict__ bias2,
    float* __restrict__ out, float* __restrict__ out2, int rows,
    float* __restrict__ gstats, float* __restrict__ gstats2,
    const float* __restrict__ bnst, const float* __restrict__ gam, const float* __restrict__ bet)
{
    constexpr int KP = K + 8;
    constexpr int KC = K / 32;
    short* wl  = (short*)smem;
    short* wl2 = wl + 64 * KP;
    float* bnA = (float*)(smem + 18432);
    float* bnD = bnA + 64;
    const int tid = threadIdx.x;

    for (int i = tid * 4; i < K * 64; i += 1024) {
        int k = i >> 6, c = i & 63;
        float4 w = *(const float4*)(W + i);
        wl[(c+0)*KP + k] = bf16r(w.x); wl[(c+1)*KP + k] = bf16r(w.y);
        wl[(c+2)*KP + k] = bf16r(w.z); wl[(c+3)*KP + k] = bf16r(w.w);
        if constexpr (DUAL) {
            float4 v = *(const float4*)(Wb + i);
            wl2[(c+0)*KP + k] = bf16r(v.x); wl2[(c+1)*KP + k] = bf16r(v.y);
            wl2[(c+2)*KP + k] = bf16r(v.z); wl2[(c+3)*KP + k] = bf16r(v.w);
        }
    }
    if constexpr (BNIN) {
        if (tid < 64) {
            float m = bnst[tid] * (1.f / NN);
            float v = bnst[64 + tid] * (1.f / NN) - m * m;
            float a = rsqrtf(v + 1e-5f) * gam[tid];
            bnA[tid] = a;
            bnD[tid] = bet[tid] - m * a;
        }
    }
    __syncthreads();

    const int lane = tid & 63, l15 = lane & 15, lhi = lane >> 4;
    const int wid = blockIdx.x * 4 + (tid >> 6);
    const int wstride = (int)gridDim.x * 4;
    const int nrb = rows >> 4;

    for (int rb = wid; rb < nrb; rb += wstride) {
        const float* ap = in + (rb * 16 + l15) * K + lhi * 8;
        bf8_t bf[KC];
#pragma unroll
        for (int kc = 0; kc < KC; ++kc) {
            float4 t0 = *(const float4*)(ap + kc * 32);
            float4 t1 = *(const float4*)(ap + kc * 32 + 4);
            if constexpr (BNIN) {
                int k0 = kc * 32 + lhi * 8;
                t0.x = fmaf(bnA[k0+0], t0.x, bnD[k0+0]);
                t0.y = fmaf(bnA[k0+1], t0.y, bnD[k0+1]);
                t0.z = fmaf(bnA[k0+2], t0.z, bnD[k0+2]);
                t0.w = fmaf(bnA[k0+3], t0.w, bnD[k0+3]);
                t1.x = fmaf(bnA[k0+4], t1.x, bnD[k0+4]);
                t1.y = fmaf(bnA[k0+5], t1.y, bnD[k0+5]);
                t1.z = fmaf(bnA[k0+6], t1.z, bnD[k0+6]);
                t1.w = fmaf(bnA[k0+7], t1.w, bnD[k0+7]);
            }
            bf8_t v;
            v[0]=bf16r(t0.x); v[1]=bf16r(t0.y); v[2]=bf16r(t0.z); v[3]=bf16r(t0.w);
            v[4]=bf16r(t1.x); v[5]=bf16r(t1.y); v[6]=bf16r(t1.z); v[7]=bf16r(t1.w);
            bf[kc] = v;
        }
        f4_t acc[4], acc2[DUAL ? 4 : 1];
#pragma unroll
        for (int ct = 0; ct < 4; ++ct) {
            acc[ct] = (f4_t){0.f,0.f,0.f,0.f};
            if constexpr (DUAL) acc2[ct] = (f4_t){0.f,0.f,0.f,0.f};
        }
#pragma unroll
        for (int ct = 0; ct < 4; ++ct) {
            const short* wp = wl + (ct * 16 + l15) * KP + lhi * 8;
#pragma unroll
            for (int kc = 0; kc < KC; ++kc) {
                bf8_t af = *(const bf8_t*)(wp + kc * 32);
                acc[ct] = __builtin_amdgcn_mfma_f32_16x16x32_bf16(af, bf[kc], acc[ct], 0, 0, 0);
            }
            if constexpr (DUAL) {
                const short* wp2 = wl2 + (ct * 16 + l15) * KP + lhi * 8;
#pragma unroll
                for (int kc = 0; kc < KC; ++kc) {
                    bf8_t af2 = *(const bf8_t*)(wp2 + kc * 32);
                    acc2[ct] = __builtin_amdgcn_mfma_f32_16x16x32_bf16(af2, bf[kc], acc2[ct], 0, 0, 0);
                }
            }
        }
        float* orow = out + (rb * 16 + l15) * 64;
#pragma unroll
        for (int ct = 0; ct < 4; ++ct) {
            int cb = ct * 16 + lhi * 4;
            f4_t a = acc[ct];
            if constexpr (BIAS) {
                float4 bb = *(const float4*)(bias + cb);
                a[0]+=bb.x; a[1]+=bb.y; a[2]+=bb.z; a[3]+=bb.w;
            }
            if constexpr (RELU) {
                a[0]=fmaxf(a[0],0.f); a[1]=fmaxf(a[1],0.f);
                a[2]=fmaxf(a[2],0.f); a[3]=fmaxf(a[3],0.f);
            }
            *(f4_t*)(orow + cb) = a;
            if constexpr (STATS) stat_red(a, cb, l15, gstats);
            if constexpr (DUAL) {
                f4_t b = acc2[ct];
                if constexpr (BIAS) {
                    float4 bb2 = *(const float4*)(bias2 + cb);
                    b[0]+=bb2.x; b[1]+=bb2.y; b[2]+=bb2.z; b[3]+=bb2.w;
                }
                if constexpr (RELU) {
                    b[0]=fmaxf(b[0],0.f); b[1]=fmaxf(b[1],0.f);
                    b[2]=fmaxf(b[2],0.f); b[3]=fmaxf(b[3],0.f);
                }
                *(f4_t*)(out2 + (rb * 16 + l15) * 64 + cb) = b;
                if constexpr (STATS) stat_red(b, cb, l15, gstats2);
            }
        }
    }
}

// ---------------- gather phase: out = relu(in[i] + sum in[src] + bias) ----------------

__device__ void gather_phase(const float* __restrict__ in, const float* __restrict__ bias,
                             float* __restrict__ out, const Params& p) {
    int l16 = threadIdx.x & 15, gbase = threadIdx.x & 48;
    int slot = (blockIdx.x * 256 + threadIdx.x) >> 4;
    int stride = (int)gridDim.x * 16;
    for (int node = slot; node < NN; node += stride) {
        int s0 = p.rowst[node], s1 = p.rowst[node + 1];
        float4 acc = ((const float4*)in)[node * 16 + l16];
        for (int e0 = s0; e0 < s1; e0 += 16) {
            int cnt = min(16, s1 - e0);
            int srcv = (l16 < cnt) ? p.csr[e0 + l16] : 0;
            for (int j = 0; j < cnt; ++j) {
                int s = __shfl(srcv, gbase + j);
                float4 hv = ((const float4*)in)[s * 16 + l16];
                acc.x += hv.x; acc.y += hv.y; acc.z += hv.z; acc.w += hv.w;
            }
        }
        float4 b = ((const float4*)bias)[l16];
        acc.x = fmaxf(acc.x + b.x, 0.f); acc.y = fmaxf(acc.y + b.y, 0.f);
        acc.z = fmaxf(acc.z + b.z, 0.f); acc.w = fmaxf(acc.w + b.w, 0.f);
        ((float4*)out)[node * 16 + l16] = acc;
    }
}

// ---------------- bn apply ----------------

__device__ void bnapply(const float* __restrict__ in, float* __restrict__ out, int rows,
                        const float* __restrict__ st, const float* __restrict__ g,
                        const float* __restrict__ b, int gtid, int nt) {
    float invr = 1.f / (float)rows;
    for (int i = gtid; i < rows * 64; i += nt) {
        int c = i & 63;
        float m = st[c] * invr;
        float var = st[64 + c] * invr - m * m;
        out[i] = (in[i] - m) * rsqrtf(var + 1e-5f) * g[c] + b[c];
    }
}

// ---------------- attention (both iterations for one graph) ----------------

struct AttnS {
    float ssl[64], sqv[64], supd[64], ssum[4];
    float sgi[192], sgh[192], red[256];
    float smax, stot;
};

__device__ void attn_graph(AttnS* S, int g, const Params& p) {
    const int tid = threadIdx.x, w = tid >> 6, lane = tid & 63;
    const float* kbuf = p.A; const float* vbuf = p.B;
    int s0 = p.segst[g], s1 = p.segst[g + 1];
    if (tid < 64) S->ssl[tid] = p.slots[g * 64 + tid];
    __syncthreads();
    for (int it = 0; it < 2; ++it) {
        float pr = 0.f;
#pragma unroll
        for (int kk = 0; kk < 16; ++kk) pr += S->ssl[w * 16 + kk] * p.Wq[(w * 16 + kk) * 64 + lane];
        S->red[tid] = pr;
        __syncthreads();
        if (tid < 64) S->sqv[tid] = S->red[tid] + S->red[64+tid] + S->red[128+tid] + S->red[192+tid];
        __syncthreads();
        float qd = S->sqv[lane];

        float m = -INFINITY;
        for (int n = s0 + w; n < s1; n += 4) {
            float pp = kbuf[n * 64 + lane] * qd;
            pp += __shfl_xor(pp, 1);  pp += __shfl_xor(pp, 2);  pp += __shfl_xor(pp, 4);
            pp += __shfl_xor(pp, 8);  pp += __shfl_xor(pp, 16); pp += __shfl_xor(pp, 32);
            pp *= 0.125f;
            if (lane == 0) p.attn[n] = pp;
            m = fmaxf(m, pp);
        }
        if (lane == 0) S->red[w] = m;
        __syncthreads();
        if (tid == 0) S->smax = fmaxf(fmaxf(S->red[0], S->red[1]), fmaxf(S->red[2], S->red[3]));
        __syncthreads();
        m = S->smax;

        float s = 0.f, upd = 0.f;
        for (int n = s0 + w; n < s1; n += 4) {
            float e = expf(p.attn[n] - m);
            if (lane == 0) p.attn[n] = e;
            s += e;
            upd += e * vbuf[n * 64 + lane];
        }
        S->red[tid] = upd;
        if (lane == 0) S->ssum[w] = s;
        __syncthreads();
        if (tid < 64) {
            float st = S->ssum[0] + S->ssum[1] + S->ssum[2] + S->ssum[3] + 1e-9f;
            if (tid == 0) S->stot = st;
            S->supd[tid] = (S->red[tid] + S->red[64+tid] + S->red[128+tid] + S->red[192+tid]) / st;
        }
        __syncthreads();

        if (it == 1) {
            float inv = 1.f / S->stot;
            for (int n = s0 + tid; n < s1; n += 256) p.attn[n] *= inv;
        }

        if (tid < 192) {
            float a = p.bih[tid], b = p.bhh[tid];
            const float* wi = &p.Wih[tid * 64];
            const float* wh = &p.Whh[tid * 64];
#pragma unroll 8
            for (int j = 0; j < 64; ++j) { a += S->supd[j] * wi[j]; b += S->ssl[j] * wh[j]; }
            S->sgi[tid] = a; S->sgh[tid] = b;
        }
        __syncthreads();
        if (tid < 64) {
            float r  = 1.f / (1.f + expf(-(S->sgi[tid] + S->sgh[tid])));
            float z  = 1.f / (1.f + expf(-(S->sgi[64+tid] + S->sgh[64+tid])));
            float nn2 = tanhf(S->sgi[128+tid] + r * S->sgh[128+tid]);
            float ns = (1.f - z) * nn2 + z * S->ssl[tid];
            S->ssl[tid] = ns;
            if (it == 1) p.slots[g * 64 + tid] = ns;
        }
        __syncthreads();
    }
}

// ---------------- the mega kernel ----------------

__global__ __launch_bounds__(256, 3) void mega_k(Params p) {
    __shared__ __align__(16) char smem[18944];
    const int tid = threadIdx.x, bid = blockIdx.x;
    const int nb = (int)gridDim.x;
    const int gtid = bid * 256 + tid;
    const int nt = nb * 256;
    int* bar = p.bar;
    int bk = 0;

    // P0: zero cursor/stats + segment bounds
    for (int i = gtid; i < NN; i += nt) p.cursor[i] = 0;
    if (gtid < 7 * 128) p.stats[gtid] = 0.f;
    if (gtid <= GG) {
        int lo = 0, hi = NN;
        while (lo < hi) { int mid = (lo + hi) >> 1; if (p.batch[mid] < gtid) lo = mid + 1; else hi = mid; }
        p.segst[gtid] = lo;
    }
    gbar(bar, ++bk);

    // P1: degree histogram
    for (int e = gtid * 4; e < EE; e += nt * 4) {
        int4 d = *(const int4*)&p.dstI[e];
        atomicAdd(&p.cursor[d.x], 1); atomicAdd(&p.cursor[d.y], 1);
        atomicAdd(&p.cursor[d.z], 1); atomicAdd(&p.cursor[d.w], 1);
    }
    gbar(bar, ++bk);

    // P2: per-chunk (256) inclusive scan
    {
        int* buf = (int*)smem;
        for (int ch = bid; ch < NCH; ch += nb) {
            int i = ch * 256 + tid;
            int v = (i < NN) ? p.cursor[i] : 0;
            buf[tid] = v; __syncthreads();
            for (int o = 1; o < 256; o <<= 1) {
                int t = (tid >= o) ? buf[tid - o] : 0;
                __syncthreads(); buf[tid] += t; __syncthreads();
            }
            if (i < NN) p.rowst[i + 1] = buf[tid];
            if (tid == 255) p.csum[ch] = buf[255];
            __syncthreads();
        }
    }
    gbar(bar, ++bk);

    // P3: scan chunk sums (block 0)
    if (bid == 0) {
        int* buf = (int*)smem;
        int v = (tid < NCH) ? p.csum[tid] : 0;
        int orig = v;
        buf[tid] = v; __syncthreads();
        for (int o = 1; o < 256; o <<= 1) {
            int t = (tid >= o) ? buf[tid - o] : 0;
            __syncthreads(); buf[tid] += t; __syncthreads();
        }
        p.bofs[tid] = buf[tid] - orig;
    }
    gbar(bar, ++bk);

    // P4: apply chunk offsets; cursor = rowstart
    for (int i = gtid; i < NN; i += nt) {
        int val = p.rowst[i + 1] + p.bofs[i >> 8];
        p.rowst[i + 1] = val;
        if (i + 1 < NN) p.cursor[i + 1] = val;
        if (i == 0) { p.rowst[0] = 0; p.cursor[0] = 0; }
    }
    gbar(bar, ++bk);

    // P5: fill CSR
    for (int e = gtid * 4; e < EE; e += nt * 4) {
        int4 d = *(const int4*)&p.dstI[e];
        int4 s = *(const int4*)&p.srcI[e];
        p.csr[atomicAdd(&p.cursor[d.x], 1)] = s.x;
        p.csr[atomicAdd(&p.cursor[d.y], 1)] = s.y;
        p.csr[atomicAdd(&p.cursor[d.z], 1)] = s.z;
        p.csr[atomicAdd(&p.cursor[d.w], 1)] = s.w;
    }
    gbar(bar, ++bk);

    float* s0 = p.stats;        float* s1 = p.stats + 128;  float* s2 = p.stats + 256;
    float* s3 = p.stats + 384;  float* s4 = p.stats + 512;  float* s5 = p.stats + 640;
    float* s6 = p.stats + 768;

    // ---- GIN layer 0 ----
    gemm_phase<128,false,false,false,false,false>(smem, p.x, p.W1_0, nullptr, nullptr, nullptr,
        p.A, nullptr, NN, nullptr, nullptr, nullptr, nullptr, nullptr);
    gbar(bar, ++bk);
    gather_phase(p.A, p.b1_0, p.B, p);
    gbar(bar, ++bk);
    gemm_phase<64,true,true,true,false,false>(smem, p.B, p.W2_0, nullptr, p.b2_0, nullptr,
        p.C, nullptr, NN, s0, nullptr, nullptr, nullptr, nullptr);
    gbar(bar, ++bk);

    // ---- GIN layer 1 ----
    gemm_phase<64,false,false,false,true,false>(smem, p.C, p.W1_r, nullptr, nullptr, nullptr,
        p.A, nullptr, NN, nullptr, nullptr, s0, p.bn_g, p.bn_b);
    gbar(bar, ++bk);
    gather_phase(p.A, p.b1_r, p.B, p);
    gbar(bar, ++bk);
    gemm_phase<64,true,true,true,false,false>(smem, p.B, p.W2_r, nullptr, p.b2_r, nullptr,
        p.D, nullptr, NN, s1, nullptr, nullptr, nullptr, nullptr);
    gbar(bar, ++bk);

    // ---- GIN layer 2 ----
    gemm_phase<64,false,false,false,true,false>(smem, p.D, p.W1_r + 64*64, nullptr, nullptr, nullptr,
        p.A, nullptr, NN, nullptr, nullptr, s1, p.bn_g + 64, p.bn_b + 64);
    gbar(bar, ++bk);
    gather_phase(p.A, p.b1_r + 64, p.B, p);
    gbar(bar, ++bk);
    gemm_phase<64,true,true,true,false,false>(smem, p.B, p.W2_r + 64*64, nullptr, p.b2_r + 64, nullptr,
        p.C, nullptr, NN, s2, nullptr, nullptr, nullptr, nullptr);   // C = z2
    gbar(bar, ++bk);

    // ---- P15: k,v DUAL GEMM (BN2 fused) + graph mean (BN2 fused) ----
    gemm_phase<64,false,false,false,true,true>(smem, p.C, p.Wk, p.Wv, nullptr, nullptr,
        p.A, p.B, NN, nullptr, nullptr, s2, p.bn_g + 128, p.bn_b + 128);
    __syncthreads();
    {
        float* red = (float*)smem;
        const int w = tid >> 6, lane = tid & 63;
        for (int g = bid; g < GG; g += nb) {
            int a0 = p.segst[g], a1 = p.segst[g + 1];
            float acc = 0.f;
            for (int n = a0 + w; n < a1; n += 4) acc += p.C[n * 64 + lane];
            red[tid] = acc; __syncthreads();
            if (tid < 64) {
                float m = s2[tid] * (1.f / NN);
                float var = s2[64 + tid] * (1.f / NN) - m * m;
                float a = rsqrtf(var + 1e-5f) * p.bn_g[128 + tid];
                float d = p.bn_b[128 + tid] - m * a;
                float mean = (red[tid] + red[64+tid] + red[128+tid] + red[192+tid]) / (float)max(a1 - a0, 1);
                p.slots[g * 64 + tid] = a * mean + d;
            }
            __syncthreads();
        }
    }
    gbar(bar, ++bk);

    // ---- P16: attention (2 iterations, per-graph) ----
    {
        AttnS* S = (AttnS*)smem;
        for (int g = bid; g < GG; g += nb) attn_graph(S, g, p);
    }
    gbar(bar, ++bk);

    // ---- P17: graph-head DUAL GEMM + noisy ----
    gemm_phase<64,true,true,true,false,true>(smem, p.slots, p.gmW, p.glW, p.gmb, p.glb,
        p.gpre1, p.gpre2, GG, s5, s6, nullptr, nullptr, nullptr);
    for (int i = gtid; i < NN * 64; i += nt) {
        int c = i & 63, n = i >> 6;
        float m = s2[c] * (1.f / NN);
        float var = s2[64 + c] * (1.f / NN) - m * m;
        float a = rsqrtf(var + 1e-5f) * p.bn_g[128 + c];
        float d = p.bn_b[128 + c] - m * a;
        p.D[i] = p.attn[n] * (a * p.C[i] + d) + p.noise[i];
    }
    gbar(bar, ++bk);

    // ---- P18: node-head DUAL GEMM ----
    gemm_phase<64,true,true,true,false,true>(smem, p.D, p.nmW, p.nlW, p.nmb, p.nlb,
        p.A, p.B, NN, s3, s4, nullptr, nullptr, nullptr);
    gbar(bar, ++bk);

    // ---- P19: final batchnorms -> outputs ----
    bnapply(p.A, p.o_nmu, NN, s3, p.pj_g,       p.pj_b,       gtid, nt);
    bnapply(p.B, p.o_nlv, NN, s4, p.pj_g + 64,  p.pj_b + 64,  gtid, nt);
    bnapply(p.gpre1, p.o_gmu, GG, s5, p.pj_g + 128, p.pj_b + 128, gtid, nt);
    bnapply(p.gpre2, p.o_glv, GG, s6, p.pj_g + 192, p.pj_b + 192, gtid, nt);
}

// ---------------- host side ----------------

extern "C" void kernel_launch(void* const* d_in, const int* in_sizes, int n_in,
                              void* d_out, int out_size, void* d_ws, size_t ws_size,
                              hipStream_t stream) {
    (void)in_sizes; (void)n_in; (void)out_size; (void)ws_size;

    Params p;
    p.x     = (const float*)d_in[0];
    const int* ei = (const int*)d_in[1];
    p.srcI  = ei;
    p.dstI  = ei + EE;
    p.batch = (const int*)d_in[2];
    p.noise = (const float*)d_in[3];
    p.W1_0  = (const float*)d_in[4];  p.b1_0 = (const float*)d_in[5];
    p.W2_0  = (const float*)d_in[6];  p.b2_0 = (const float*)d_in[7];
    p.W1_r  = (const float*)d_in[8];  p.b1_r = (const float*)d_in[9];
    p.W2_r  = (const float*)d_in[10]; p.b2_r = (const float*)d_in[11];
    p.bn_g  = (const float*)d_in[12]; p.bn_b = (const float*)d_in[13];
    p.Wq    = (const float*)d_in[14]; p.Wk   = (const float*)d_in[15];
    p.Wv    = (const float*)d_in[16];
    p.Wih   = (const float*)d_in[17]; p.Whh  = (const float*)d_in[18];
    p.bih   = (const float*)d_in[19]; p.bhh  = (const float*)d_in[20];
    p.nmW   = (const float*)d_in[21]; p.nmb  = (const float*)d_in[22];
    p.nlW   = (const float*)d_in[23]; p.nlb  = (const float*)d_in[24];
    p.gmW   = (const float*)d_in[25]; p.gmb  = (const float*)d_in[26];
    p.glW   = (const float*)d_in[27]; p.glb  = (const float*)d_in[28];
    p.pj_g  = (const float*)d_in[29]; p.pj_b = (const float*)d_in[30];

    float* ws = (float*)d_ws;
    p.A      = ws;
    p.B      = p.A + NN * 64;
    p.C      = p.B + NN * 64;
    p.D      = p.C + NN * 64;
    p.slots  = p.D + NN * 64;
    p.gpre1  = p.slots + GG * 64;
    p.gpre2  = p.gpre1 + GG * 64;
    p.attn   = p.gpre2 + GG * 64;
    p.stats  = p.attn + NN;
    p.segst  = (int*)(p.stats + 7 * 128);
    p.rowst  = p.segst + (GG + 1);
    p.cursor = p.rowst + (NN + 1);
    p.csum   = p.cursor + NN;
    p.bofs   = p.csum + 256;
    p.bar    = p.bofs + 256;
    p.csr    = p.bar + 64;

    float* outp = (float*)d_out;
    p.o_nmu = outp;
    p.o_nlv = outp + NN * 64;
    p.o_gmu = outp + 2 * NN * 64;
    p.o_glv = outp + 2 * NN * 64 + GG * 64;

    int maxb = 0;
    hipError_t e = hipOccupancyMaxActiveBlocksPerMultiprocessor(&maxb, mega_k, 256, 0);
    int nb = 768;
    if (e == hipSuccess && maxb > 0) {
        int cap = maxb * 256;   // 256 CUs on MI355X
        if (cap < nb) nb = cap;
    } else {
        nb = 256;               // ultra-conservative co-residency fallback
    }

    binit_k<<<1, 32, 0, stream>>>(p.bar);
    mega_k<<<nb, 256, 0, stream>>>(p);
}

// Round 7
// 1667.645 us; speedup vs baseline: 1.2464x; 1.2464x over previous
//
#include <hip/hip_runtime.h>

#define NN 50000
#define EE 800000
#define FF 128
#define DD 64
#define GG 512

typedef __attribute__((ext_vector_type(8))) short bf8_t;
typedef __attribute__((ext_vector_type(4))) float f4_t;

__device__ __forceinline__ short bf16r(float f) {
    unsigned u = __builtin_bit_cast(unsigned, f);
    u += 0x7fffu + ((u >> 16) & 1u);   // RNE
    return (short)(u >> 16);
}

// ---------------- init: zero cursor + all stats buffers (replay-safe) ----------------

__global__ void zero_all_k(int* __restrict__ cursor, float* __restrict__ stats_all) {
    int i = blockIdx.x * blockDim.x + threadIdx.x;
    if (i < NN) cursor[i] = 0;
    if (i < 7 * 128) stats_all[i] = 0.f;
}

// ---------------- CSR build (counting sort by dst), 4 edges/thread ----------------

__global__ void hist_k(const int* __restrict__ dst, int* __restrict__ deg) {
    int e = (blockIdx.x * 256 + threadIdx.x) * 4;
    if (e + 4 <= EE) {
        int4 d = *(const int4*)&dst[e];
        atomicAdd(&deg[d.x], 1); atomicAdd(&deg[d.y], 1);
        atomicAdd(&deg[d.z], 1); atomicAdd(&deg[d.w], 1);
    } else {
        for (; e < EE; ++e) atomicAdd(&deg[dst[e]], 1);
    }
}

__global__ __launch_bounds__(1024) void scanA_k(const int* __restrict__ deg,
                                                int* __restrict__ rowstart,
                                                int* __restrict__ blocksum) {
    __shared__ int buf[1024];
    int tid = threadIdx.x;
    int base = blockIdx.x * 1024;
    int v = (base + tid < NN) ? deg[base + tid] : 0;
    buf[tid] = v;
    __syncthreads();
    for (int o = 1; o < 1024; o <<= 1) {
        int t = (tid >= o) ? buf[tid - o] : 0;
        __syncthreads();
        buf[tid] += t;
        __syncthreads();
    }
    if (base + tid < NN) rowstart[base + tid + 1] = buf[tid];
    if (tid == 1023) blocksum[blockIdx.x] = buf[1023];
}

__global__ void scanB_k(const int* __restrict__ blocksum, int* __restrict__ bofs, int nb) {
    int lane = threadIdx.x;  // 64 threads
    int v = (lane < nb) ? blocksum[lane] : 0;
    int orig = v;
    for (int o = 1; o < 64; o <<= 1) {
        int t = __shfl_up(v, o);
        if (lane >= o) v += t;
    }
    if (lane < nb) bofs[lane] = v - orig;
}

__global__ void scanC_k(int* __restrict__ rowstart, const int* __restrict__ bofs,
                        int* __restrict__ cursor) {
    int i = blockIdx.x * blockDim.x + threadIdx.x;
    if (i >= NN) return;
    int val = rowstart[i + 1] + bofs[i >> 10];
    rowstart[i + 1] = val;
    if (i + 1 < NN) cursor[i + 1] = val;
    if (i == 0) { rowstart[0] = 0; cursor[0] = 0; }
}

__global__ void fill_k(const int* __restrict__ src, const int* __restrict__ dst,
                       int* __restrict__ cursor, int* __restrict__ csr_src) {
    int e = (blockIdx.x * 256 + threadIdx.x) * 4;
    if (e + 4 <= EE) {
        int4 d = *(const int4*)&dst[e];
        int4 s = *(const int4*)&src[e];
        int p0 = atomicAdd(&cursor[d.x], 1);
        int p1 = atomicAdd(&cursor[d.y], 1);
        int p2 = atomicAdd(&cursor[d.z], 1);
        int p3 = atomicAdd(&cursor[d.w], 1);
        csr_src[p0] = s.x; csr_src[p1] = s.y; csr_src[p2] = s.z; csr_src[p3] = s.w;
    } else {
        for (; e < EE; ++e) { int p = atomicAdd(&cursor[dst[e]], 1); csr_src[p] = src[e]; }
    }
}

// ---------------- GIN aggregation, 16 lanes/node, float4: out = relu(in[i]+sum in[src]+bias) ----------------

__global__ __launch_bounds__(256) void gin_agg_br_k(const float* __restrict__ in,
                                                    const int* __restrict__ rowstart,
                                                    const int* __restrict__ csr_src,
                                                    const float* __restrict__ bias,
                                                    float* __restrict__ out) {
    int gt    = blockIdx.x * 256 + threadIdx.x;
    int node  = gt >> 4;          // 4 nodes per wave, 16 lanes each
    int l16   = threadIdx.x & 15;
    int gbase = threadIdx.x & 48; // group base lane within wave
    if (node >= NN) return;
    int s0 = rowstart[node], s1 = rowstart[node + 1];
    float4 acc = ((const float4*)in)[node * 16 + l16];
    for (int e0 = s0; e0 < s1; e0 += 16) {
        int cnt  = min(16, s1 - e0);
        int srcv = (l16 < cnt) ? csr_src[e0 + l16] : 0;
        for (int j = 0; j < cnt; ++j) {
            int s = __shfl(srcv, gbase + j);
            float4 hv = ((const float4*)in)[s * 16 + l16];
            acc.x += hv.x; acc.y += hv.y; acc.z += hv.z; acc.w += hv.w;
        }
    }
    float4 b = ((const float4*)bias)[l16];
    acc.x = fmaxf(acc.x + b.x, 0.f); acc.y = fmaxf(acc.y + b.y, 0.f);
    acc.z = fmaxf(acc.z + b.z, 0.f); acc.w = fmaxf(acc.w + b.w, 0.f);
    ((float4*)out)[node * 16 + l16] = acc;
}

// ---------------- per-lane stats reduce (over 16 row-lanes) + atomic ----------------

__device__ __forceinline__ void stat_red(f4_t a, int cb, int l15, float* gs) {
    f4_t s = a, q;
    q[0] = a[0]*a[0]; q[1] = a[1]*a[1]; q[2] = a[2]*a[2]; q[3] = a[3]*a[3];
#pragma unroll
    for (int o = 1; o < 16; o <<= 1) {
        s[0] += __shfl_xor(s[0], o); s[1] += __shfl_xor(s[1], o);
        s[2] += __shfl_xor(s[2], o); s[3] += __shfl_xor(s[3], o);
        q[0] += __shfl_xor(q[0], o); q[1] += __shfl_xor(q[1], o);
        q[2] += __shfl_xor(q[2], o); q[3] += __shfl_xor(q[3], o);
    }
    if (l15 == 0) {
        atomicAdd(&gs[cb+0], s[0]); atomicAdd(&gs[cb+1], s[1]);
        atomicAdd(&gs[cb+2], s[2]); atomicAdd(&gs[cb+3], s[3]);
        atomicAdd(&gs[64+cb+0], q[0]); atomicAdd(&gs[64+cb+1], q[1]);
        atomicAdd(&gs[64+cb+2], q[2]); atomicAdd(&gs[64+cb+3], q[3]);
    }
}

// ---------------- MFMA GEMM: out[rows x 64] = act(T(in)[rows x K] @ W + b) ----------------
// W staged once per block into LDS, transposed bf16, pad 8 (2-way-max bank aliasing = free).
// Operand roles: A = W^T (from LDS), B = activation rows (global float4 -> bf16 in reg).
// Lane's C regs = 4 consecutive output cols -> float4 stores (no partial-line RMW).
// T(in): BNIN (columnwise a*x+d from bnst/gam/bet), then ROWSCALE (attn[row]*x + noise).
// rows must be a multiple of 16. One wave computes a 16-row x 64-col tile per iteration.

template<int K, bool BIAS, bool RELU, bool STATS, bool BNIN, bool ROWSCALE, bool DUAL>
__global__ __launch_bounds__(256) void mgemm_k(
    const float* __restrict__ in, const float* __restrict__ W, const float* __restrict__ Wb,
    const float* __restrict__ bias, const float* __restrict__ bias2,
    float* __restrict__ out, float* __restrict__ out2, int rows,
    float* __restrict__ gstats, float* __restrict__ gstats2,
    const float* __restrict__ bnst, const float* __restrict__ gam,
    const float* __restrict__ bet,
    const float* __restrict__ attn, const float* __restrict__ noise)
{
    constexpr int KP = K + 8;
    constexpr int KC = K / 32;
    __shared__ __align__(16) short wl[64 * KP];
    __shared__ __align__(16) short wl2[DUAL ? 64 * KP : 8];
    __shared__ float bnA[BNIN ? 64 : 1];
    __shared__ float bnD[BNIN ? 64 : 1];
    const int tid = threadIdx.x;

    for (int i = tid * 4; i < K * 64; i += 1024) {
        int k = i >> 6, c = i & 63;
        float4 w = *(const float4*)(W + i);
        wl[(c+0)*KP + k] = bf16r(w.x); wl[(c+1)*KP + k] = bf16r(w.y);
        wl[(c+2)*KP + k] = bf16r(w.z); wl[(c+3)*KP + k] = bf16r(w.w);
        if constexpr (DUAL) {
            float4 v = *(const float4*)(Wb + i);
            wl2[(c+0)*KP + k] = bf16r(v.x); wl2[(c+1)*KP + k] = bf16r(v.y);
            wl2[(c+2)*KP + k] = bf16r(v.z); wl2[(c+3)*KP + k] = bf16r(v.w);
        }
    }
    if constexpr (BNIN) {
        if (tid < 64) {
            float m = bnst[tid] * (1.f / NN);
            float v = bnst[64 + tid] * (1.f / NN) - m * m;
            float a = rsqrtf(v + 1e-5f) * gam[tid];
            bnA[tid] = a;
            bnD[tid] = bet[tid] - m * a;
        }
    }
    __syncthreads();

    const int lane = tid & 63, l15 = lane & 15, lhi = lane >> 4;
    const int wid = blockIdx.x * 4 + (tid >> 6);
    const int wstride = (int)gridDim.x * 4;
    const int nrb = rows >> 4;

    for (int rb = wid; rb < nrb; rb += wstride) {
        const int row = rb * 16 + l15;
        const float* ap = in + row * K + lhi * 8;
        float at;
        const float* npo;
        if constexpr (ROWSCALE) { at = attn[row]; npo = noise + row * K + lhi * 8; }
        bf8_t bf[KC];
#pragma unroll
        for (int kc = 0; kc < KC; ++kc) {
            float4 t0 = *(const float4*)(ap + kc * 32);
            float4 t1 = *(const float4*)(ap + kc * 32 + 4);
            if constexpr (BNIN) {
                int k0 = kc * 32 + lhi * 8;
                t0.x = fmaf(bnA[k0+0], t0.x, bnD[k0+0]);
                t0.y = fmaf(bnA[k0+1], t0.y, bnD[k0+1]);
                t0.z = fmaf(bnA[k0+2], t0.z, bnD[k0+2]);
                t0.w = fmaf(bnA[k0+3], t0.w, bnD[k0+3]);
                t1.x = fmaf(bnA[k0+4], t1.x, bnD[k0+4]);
                t1.y = fmaf(bnA[k0+5], t1.y, bnD[k0+5]);
                t1.z = fmaf(bnA[k0+6], t1.z, bnD[k0+6]);
                t1.w = fmaf(bnA[k0+7], t1.w, bnD[k0+7]);
            }
            if constexpr (ROWSCALE) {
                float4 n0 = *(const float4*)(npo + kc * 32);
                float4 n1 = *(const float4*)(npo + kc * 32 + 4);
                t0.x = fmaf(at, t0.x, n0.x); t0.y = fmaf(at, t0.y, n0.y);
                t0.z = fmaf(at, t0.z, n0.z); t0.w = fmaf(at, t0.w, n0.w);
                t1.x = fmaf(at, t1.x, n1.x); t1.y = fmaf(at, t1.y, n1.y);
                t1.z = fmaf(at, t1.z, n1.z); t1.w = fmaf(at, t1.w, n1.w);
            }
            bf8_t v;
            v[0]=bf16r(t0.x); v[1]=bf16r(t0.y); v[2]=bf16r(t0.z); v[3]=bf16r(t0.w);
            v[4]=bf16r(t1.x); v[5]=bf16r(t1.y); v[6]=bf16r(t1.z); v[7]=bf16r(t1.w);
            bf[kc] = v;
        }
        f4_t acc[4], acc2[DUAL ? 4 : 1];
#pragma unroll
        for (int ct = 0; ct < 4; ++ct) {
            acc[ct] = (f4_t){0.f,0.f,0.f,0.f};
            if constexpr (DUAL) acc2[ct] = (f4_t){0.f,0.f,0.f,0.f};
        }
#pragma unroll
        for (int ct = 0; ct < 4; ++ct) {
            const short* wp = wl + (ct * 16 + l15) * KP + lhi * 8;
#pragma unroll
            for (int kc = 0; kc < KC; ++kc) {
                bf8_t af = *(const bf8_t*)(wp + kc * 32);
                acc[ct] = __builtin_amdgcn_mfma_f32_16x16x32_bf16(af, bf[kc], acc[ct], 0, 0, 0);
            }
            if constexpr (DUAL) {
                const short* wp2 = wl2 + (ct * 16 + l15) * KP + lhi * 8;
#pragma unroll
                for (int kc = 0; kc < KC; ++kc) {
                    bf8_t af2 = *(const bf8_t*)(wp2 + kc * 32);
                    acc2[ct] = __builtin_amdgcn_mfma_f32_16x16x32_bf16(af2, bf[kc], acc2[ct], 0, 0, 0);
                }
            }
        }
        float* orow = out + row * 64;
#pragma unroll
        for (int ct = 0; ct < 4; ++ct) {
            int cb = ct * 16 + lhi * 4;
            f4_t a = acc[ct];
            if constexpr (BIAS) {
                float4 bb = *(const float4*)(bias + cb);
                a[0]+=bb.x; a[1]+=bb.y; a[2]+=bb.z; a[3]+=bb.w;
            }
            if constexpr (RELU) {
                a[0]=fmaxf(a[0],0.f); a[1]=fmaxf(a[1],0.f);
                a[2]=fmaxf(a[2],0.f); a[3]=fmaxf(a[3],0.f);
            }
            *(f4_t*)(orow + cb) = a;
            if constexpr (STATS) stat_red(a, cb, l15, gstats);
            if constexpr (DUAL) {
                f4_t b = acc2[ct];
                if constexpr (BIAS) {
                    float4 bb2 = *(const float4*)(bias2 + cb);
                    b[0]+=bb2.x; b[1]+=bb2.y; b[2]+=bb2.z; b[3]+=bb2.w;
                }
                if constexpr (RELU) {
                    b[0]=fmaxf(b[0],0.f); b[1]=fmaxf(b[1],0.f);
                    b[2]=fmaxf(b[2],0.f); b[3]=fmaxf(b[3],0.f);
                }
                *(f4_t*)(out2 + row * 64 + cb) = b;
                if constexpr (STATS) stat_red(b, cb, l15, gstats2);
            }
        }
    }
}

// ---------------- batchnorm apply ----------------

__global__ void bn_apply_k(const float* __restrict__ in, float* __restrict__ out, int rows,
                           const float* __restrict__ stats, const float* __restrict__ gamma,
                           const float* __restrict__ beta) {
    int n = rows * 64;
    float invr = 1.f / (float)rows;
    for (int i = blockIdx.x * blockDim.x + threadIdx.x; i < n; i += gridDim.x * blockDim.x) {
        int c = i & 63;
        float m   = stats[c] * invr;
        float var = stats[64 + c] * invr - m * m;
        out[i] = (in[i] - m) * rsqrtf(var + 1e-5f) * gamma[c] + beta[c];
    }
}

// ---------------- segment boundaries (batch is sorted) ----------------

__global__ void seg_bounds_k(const int* __restrict__ batch, int* __restrict__ segstart) {
    int g = blockIdx.x * blockDim.x + threadIdx.x;
    if (g > GG) return;
    int lo = 0, hi = NN;
    while (lo < hi) {
        int mid = (lo + hi) >> 1;
        if (batch[mid] < g) lo = mid + 1; else hi = mid;
    }
    segstart[g] = lo;
}

// ---------------- mean pooling with fused BN affine: slots = a*mean(z)+d ----------------

__global__ __launch_bounds__(256) void graph_mean_bn_k(const float* __restrict__ z,
                                                       const int* __restrict__ segst,
                                                       const float* __restrict__ stats,
                                                       const float* __restrict__ gamma,
                                                       const float* __restrict__ beta,
                                                       float* __restrict__ slots) {
    int g = blockIdx.x, tid = threadIdx.x, w = tid >> 6, lane = tid & 63;
    int s0 = segst[g], s1 = segst[g + 1];
    float acc = 0.f;
    for (int n = s0 + w; n < s1; n += 4) acc += z[n * 64 + lane];
    __shared__ float red[256];
    red[tid] = acc;
    __syncthreads();
    if (tid < 64) {
        float m   = stats[tid] * (1.f / NN);
        float var = stats[64 + tid] * (1.f / NN) - m * m;
        float a   = rsqrtf(var + 1e-5f) * gamma[tid];
        float d   = beta[tid] - m * a;
        float mean = (red[tid] + red[64 + tid] + red[128 + tid] + red[192 + tid])
                   / (float)max(s1 - s0, 1);
        slots[g * 64 + tid] = a * mean + d;
    }
}

// ---------------- fused attention iteration: q -> logits -> softmax -> updates -> GRU ----------------

__global__ __launch_bounds__(256) void attn_iter_k(
    const float* __restrict__ kbuf, const float* __restrict__ vbuf,
    float* __restrict__ slots, const int* __restrict__ segst,
    const float* __restrict__ Wq,
    const float* __restrict__ Wih, const float* __restrict__ Whh,
    const float* __restrict__ bih, const float* __restrict__ bhh,
    float* __restrict__ attn, int final_iter)
{
    int g = blockIdx.x, tid = threadIdx.x, w = tid >> 6, lane = tid & 63;
    __shared__ float ssl[64], sq[64], sred[256], supd[64], ssum[4];
    __shared__ float sgi[192], sgh[192];
    __shared__ float smax, sstot;

    if (tid < 64) ssl[tid] = slots[g * 64 + tid];
    __syncthreads();
    {
        float p = 0.f;
#pragma unroll
        for (int kk = 0; kk < 16; ++kk) p += ssl[w * 16 + kk] * Wq[(w * 16 + kk) * 64 + lane];
        sred[tid] = p;
    }
    __syncthreads();
    if (tid < 64) sq[tid] = sred[tid] + sred[64 + tid] + sred[128 + tid] + sred[192 + tid];
    __syncthreads();

    int s0 = segst[g], s1 = segst[g + 1];
    float qd = sq[lane];

    float m = -INFINITY;
    for (int n = s0 + w; n < s1; n += 4) {
        float p = kbuf[n * 64 + lane] * qd;
        p += __shfl_xor(p, 1);  p += __shfl_xor(p, 2);  p += __shfl_xor(p, 4);
        p += __shfl_xor(p, 8);  p += __shfl_xor(p, 16); p += __shfl_xor(p, 32);
        p *= 0.125f;  // 1/sqrt(64)
        if (lane == 0) attn[n] = p;
        m = fmaxf(m, p);
    }
    if (lane == 0) sred[w] = m;
    __syncthreads();
    if (tid == 0) smax = fmaxf(fmaxf(sred[0], sred[1]), fmaxf(sred[2], sred[3]));
    __syncthreads();
    m = smax;

    float s = 0.f, upd = 0.f;
    for (int n = s0 + w; n < s1; n += 4) {
        float e = expf(attn[n] - m);
        if (lane == 0) attn[n] = e;
        s += e;
        upd += e * vbuf[n * 64 + lane];
    }
    sred[tid] = upd;
    if (lane == 0) ssum[w] = s;
    __syncthreads();
    if (tid < 64) {
        float st = ssum[0] + ssum[1] + ssum[2] + ssum[3] + 1e-9f;
        if (tid == 0) sstot = st;
        supd[tid] = (sred[tid] + sred[64 + tid] + sred[128 + tid] + sred[192 + tid]) / st;
    }
    __syncthreads();

    if (final_iter) {
        float inv = 1.f / sstot;
        for (int n = s0 + tid; n < s1; n += 256) attn[n] *= inv;
    }

    if (tid < 192) {
        float a = bih[tid], b = bhh[tid];
        const float* wi = &Wih[tid * 64];
        const float* wh = &Whh[tid * 64];
#pragma unroll 8
        for (int j = 0; j < 64; ++j) { a += supd[j] * wi[j]; b += ssl[j] * wh[j]; }
        sgi[tid] = a; sgh[tid] = b;
    }
    __syncthreads();
    if (tid < 64) {
        float r  = 1.f / (1.f + expf(-(sgi[tid] + sgh[tid])));
        float z  = 1.f / (1.f + expf(-(sgi[64 + tid] + sgh[64 + tid])));
        float nn = tanhf(sgi[128 + tid] + r * sgh[128 + tid]);
        slots[g * 64 + tid] = (1.f - z) * nn + z * ssl[tid];
    }
}

// ---------------- host side ----------------

extern "C" void kernel_launch(void* const* d_in, const int* in_sizes, int n_in,
                              void* d_out, int out_size, void* d_ws, size_t ws_size,
                              hipStream_t stream) {
    (void)in_sizes; (void)n_in; (void)out_size; (void)ws_size;

    const float* x      = (const float*)d_in[0];
    const int*   ei     = (const int*)d_in[1];
    const int*   srcI   = ei;
    const int*   dstI   = ei + EE;
    const int*   batch  = (const int*)d_in[2];
    const float* noise  = (const float*)d_in[3];
    const float* W1_0   = (const float*)d_in[4];
    const float* b1_0   = (const float*)d_in[5];
    const float* W2_0   = (const float*)d_in[6];
    const float* b2_0   = (const float*)d_in[7];
    const float* W1_r   = (const float*)d_in[8];
    const float* b1_r   = (const float*)d_in[9];
    const float* W2_r   = (const float*)d_in[10];
    const float* b2_r   = (const float*)d_in[11];
    const float* bn_g   = (const float*)d_in[12];
    const float* bn_b   = (const float*)d_in[13];
    const float* Wq     = (const float*)d_in[14];
    const float* Wk     = (const float*)d_in[15];
    const float* Wv     = (const float*)d_in[16];
    const float* Wih    = (const float*)d_in[17];
    const float* Whh    = (const float*)d_in[18];
    const float* bih    = (const float*)d_in[19];
    const float* bhh    = (const float*)d_in[20];
    const float* nmW    = (const float*)d_in[21];
    const float* nmb    = (const float*)d_in[22];
    const float* nlW    = (const float*)d_in[23];
    const float* nlb    = (const float*)d_in[24];
    const float* gmW    = (const float*)d_in[25];
    const float* gmb    = (const float*)d_in[26];
    const float* glW    = (const float*)d_in[27];
    const float* glb    = (const float*)d_in[28];
    const float* pj_g   = (const float*)d_in[29];
    const float* pj_b   = (const float*)d_in[30];

    float* ws      = (float*)d_ws;
    float* B0      = ws;                       // NN*DD
    float* B1      = B0 + NN * DD;             // NN*DD
    float* B2      = B1 + NN * DD;             // NN*DD
    float* slots   = B2 + NN * DD;             // GG*DD
    float* gpre1   = slots + GG * DD;          // GG*DD
    float* gpre2   = gpre1 + GG * DD;          // GG*DD
    float* attn    = gpre2 + GG * DD;          // NN
    float* stats   = attn + NN;                // 7*128
    int*   segst   = (int*)(stats + 7 * 128);  // GG+1
    int*   rowst   = segst + GG + 1;           // NN+1
    int*   cursor  = rowst + NN + 1;           // NN
    int*   bsum    = cursor + NN;              // 64
    int*   bofs    = bsum + 64;                // 64
    int*   csr_src = bofs + 64;                // EE

    float* s0 = stats, *s1 = stats + 128, *s2 = stats + 256, *s3 = stats + 384,
         * s4 = stats + 512, *s5 = stats + 640, *s6 = stats + 768;

    float* outp = (float*)d_out;
    float* out_nmu = outp;
    float* out_nlv = outp + NN * DD;
    float* out_gmu = outp + 2 * NN * DD;
    float* out_glv = outp + 2 * NN * DD + GG * DD;

    constexpr int NB = (NN + 1023) / 1024;  // 49 scan chunks
    constexpr int GE4 = (EE / 4 + 255) / 256;
    const float* np = nullptr;
    float* zp = nullptr;

#define GK(...) <<<__VA_ARGS__, 0, stream>>>
    // ---------- init + CSR build + segments ----------
    zero_all_k GK((NN + 255) / 256, 256)(cursor, stats);
    hist_k GK(GE4, 256)(dstI, cursor);
    scanA_k GK(NB, 1024)(cursor, rowst, bsum);
    scanB_k GK(1, 64)(bsum, bofs, NB);
    scanC_k GK((NN + 255) / 256, 256)(rowst, bofs, cursor);
    fill_k GK(GE4, 256)(srcI, dstI, cursor, csr_src);
    seg_bounds_k GK(3, 256)(batch, segst);

    // ---------- GIN layer 0 (GEMM-first: gather on 64-wide) ----------
    mgemm_k<128,false,false,false,false,false,false> GK(782, 256)
        (x, W1_0, np, np, np, B0, zp, NN, zp, zp, np, np, np, np, np);
    gin_agg_br_k GK(3125, 256)(B0, rowst, csr_src, b1_0, B1);
    mgemm_k<64,true,true,true,false,false,false> GK(782, 256)
        (B1, W2_0, np, b2_0, np, B2, zp, NN, s0, zp, np, np, np, np, np);

    // ---------- GIN layer 1 (BN0 affine fused into A-load) ----------
    mgemm_k<64,false,false,false,true,false,false> GK(782, 256)
        (B2, W1_r, np, np, np, B0, zp, NN, zp, zp, s0, bn_g + 0, bn_b + 0, np, np);
    gin_agg_br_k GK(3125, 256)(B0, rowst, csr_src, b1_r, B1);
    mgemm_k<64,true,true,true,false,false,false> GK(782, 256)
        (B1, W2_r, np, b2_r, np, B2, zp, NN, s1, zp, np, np, np, np, np);

    // ---------- GIN layer 2 ----------
    mgemm_k<64,false,false,false,true,false,false> GK(782, 256)
        (B2, W1_r + DD * DD, np, np, np, B0, zp, NN, zp, zp, s1, bn_g + 64, bn_b + 64, np, np);
    gin_agg_br_k GK(3125, 256)(B0, rowst, csr_src, b1_r + DD, B1);
    mgemm_k<64,true,true,true,false,false,false> GK(782, 256)
        (B1, W2_r + DD * DD, np, b2_r + DD, np, B2, zp, NN, s2, zp, np, np, np, np, np);
    // B2 = z2 (pre-BN); final BN affine (s2, bn[2]) fused into all consumers.

    // ---------- summary maker ----------
    graph_mean_bn_k GK(GG, 256)(B2, segst, s2, bn_g + 128, bn_b + 128, slots);
    mgemm_k<64,false,false,false,true,false,true> GK(782, 256)   // k,v in one pass
        (B2, Wk, Wv, np, np, B0, B1, NN, zp, zp, s2, bn_g + 128, bn_b + 128, np, np);
    attn_iter_k GK(GG, 256)(B0, B1, slots, segst, Wq, Wih, Whh, bih, bhh, attn, 0);
    attn_iter_k GK(GG, 256)(B0, B1, slots, segst, Wq, Wih, Whh, bih, bhh, attn, 1);

    // ---------- node heads (noisy = attn*BN(z)+noise fused into A-load; DUAL) ----------
    mgemm_k<64,true,true,true,true,true,true> GK(782, 256)
        (B2, nmW, nlW, nmb, nlb, B0, B1, NN, s3, s4, s2, bn_g + 128, bn_b + 128, attn, noise);
    bn_apply_k GK(2048, 256)(B0, out_nmu, NN, s3, pj_g + 0, pj_b + 0);
    bn_apply_k GK(2048, 256)(B1, out_nlv, NN, s4, pj_g + 64, pj_b + 64);

    // ---------- graph heads ----------
    mgemm_k<64,true,true,true,false,false,true> GK(8, 256)
        (slots, gmW, glW, gmb, glb, gpre1, gpre2, GG, s5, s6, np, np, np, np, np);
    bn_apply_k GK(128, 256)(gpre1, out_gmu, GG, s5, pj_g + 128, pj_b + 128);
    bn_apply_k GK(128, 256)(gpre2, out_glv, GG, s6, pj_g + 192, pj_b + 192);
#undef GK
}

// Round 8
// 516.324 us; speedup vs baseline: 4.0256x; 3.2298x over previous
//
#include <hip/hip_runtime.h>

#define NN 50000
#define EE 800000
#define FF 128
#define DD 64
#define GG 512

// ---------------- init: zero cursor + all stats buffers (replay-safe) ----------------

__global__ void zero_all_k(int* __restrict__ cursor, float* __restrict__ stats_all) {
    int i = blockIdx.x * blockDim.x + threadIdx.x;
    if (i < NN) cursor[i] = 0;
    if (i < 7 * 128) stats_all[i] = 0.f;
}

// ---------------- CSR build (counting sort by dst), 2 edges/thread ----------------

__global__ void hist_k(const int* __restrict__ dst, int* __restrict__ deg) {
    int e = (blockIdx.x * 256 + threadIdx.x) * 2;
    if (e + 2 <= EE) {
        int2 d = *(const int2*)&dst[e];
        atomicAdd(&deg[d.x], 1); atomicAdd(&deg[d.y], 1);
    } else {
        for (; e < EE; ++e) atomicAdd(&deg[dst[e]], 1);
    }
}

__global__ __launch_bounds__(1024) void scanA_k(const int* __restrict__ deg,
                                                int* __restrict__ rowstart,
                                                int* __restrict__ blocksum) {
    __shared__ int buf[1024];
    int tid = threadIdx.x;
    int base = blockIdx.x * 1024;
    int v = (base + tid < NN) ? deg[base + tid] : 0;
    buf[tid] = v;
    __syncthreads();
    for (int o = 1; o < 1024; o <<= 1) {
        int t = (tid >= o) ? buf[tid - o] : 0;
        __syncthreads();
        buf[tid] += t;
        __syncthreads();
    }
    if (base + tid < NN) rowstart[base + tid + 1] = buf[tid];
    if (tid == 1023) blocksum[blockIdx.x] = buf[1023];
}

__global__ void scanB_k(const int* __restrict__ blocksum, int* __restrict__ bofs, int nb) {
    int lane = threadIdx.x;  // 64 threads
    int v = (lane < nb) ? blocksum[lane] : 0;
    int orig = v;
    for (int o = 1; o < 64; o <<= 1) {
        int t = __shfl_up(v, o);
        if (lane >= o) v += t;
    }
    if (lane < nb) bofs[lane] = v - orig;
}

__global__ void scanC_k(int* __restrict__ rowstart, const int* __restrict__ bofs,
                        int* __restrict__ cursor) {
    int i = blockIdx.x * blockDim.x + threadIdx.x;
    if (i >= NN) return;
    int val = rowstart[i + 1] + bofs[i >> 10];
    rowstart[i + 1] = val;
    if (i + 1 < NN) cursor[i + 1] = val;
    if (i == 0) { rowstart[0] = 0; cursor[0] = 0; }
}

__global__ void fill_k(const int* __restrict__ src, const int* __restrict__ dst,
                       int* __restrict__ cursor, int* __restrict__ csr_src) {
    int e = (blockIdx.x * 256 + threadIdx.x) * 2;
    if (e + 2 <= EE) {
        int2 d = *(const int2*)&dst[e];
        int2 s = *(const int2*)&src[e];
        int p0 = atomicAdd(&cursor[d.x], 1);
        int p1 = atomicAdd(&cursor[d.y], 1);
        csr_src[p0] = s.x; csr_src[p1] = s.y;
    } else {
        for (; e < EE; ++e) { int p = atomicAdd(&cursor[dst[e]], 1); csr_src[p] = src[e]; }
    }
}

// ---------------- GIN aggregation, 16 lanes/node, float4: out = relu(in[i]+sum in[src]+bias) ----------------

__global__ __launch_bounds__(256) void gin_agg_br_k(const float* __restrict__ in,
                                                    const int* __restrict__ rowstart,
                                                    const int* __restrict__ csr_src,
                                                    const float* __restrict__ bias,
                                                    float* __restrict__ out) {
    int gt    = blockIdx.x * 256 + threadIdx.x;
    int node  = gt >> 4;          // 4 nodes per wave, 16 lanes each
    int l16   = threadIdx.x & 15;
    int gbase = threadIdx.x & 48; // group base lane within wave
    if (node >= NN) return;
    int s0 = rowstart[node], s1 = rowstart[node + 1];
    float4 acc = ((const float4*)in)[node * 16 + l16];
    for (int e0 = s0; e0 < s1; e0 += 16) {
        int cnt  = min(16, s1 - e0);
        int srcv = (l16 < cnt) ? csr_src[e0 + l16] : 0;
        for (int j = 0; j < cnt; ++j) {
            int s = __shfl(srcv, gbase + j);
            float4 hv = ((const float4*)in)[s * 16 + l16];
            acc.x += hv.x; acc.y += hv.y; acc.z += hv.z; acc.w += hv.w;
        }
    }
    float4 b = ((const float4*)bias)[l16];
    acc.x = fmaxf(acc.x + b.x, 0.f); acc.y = fmaxf(acc.y + b.y, 0.f);
    acc.z = fmaxf(acc.z + b.z, 0.f); acc.w = fmaxf(acc.w + b.w, 0.f);
    ((float4*)out)[node * 16 + l16] = acc;
}

// ---------------- skinny fp32 GEMM: out[rows x 64] = act(T(in)[rows x K] @ W + b) ----------------
// T(in): BNIN (columnwise affine a*x+d), then ROWSCALE (attn[row]*x + noise).
// STATS: per-column sum/sumsq of stored outputs -> gstats (pre-zeroed).
// DUAL: second W/bias/out/stats sharing the same input pass.
// Inner loop: k in chunks of 4; sIn read as float4 (KP=K+4 keeps 16B alignment, <=2-way
// bank aliasing = free); 8 ds_read_b128 per 64 FMAs -> VALU-dominant.

__device__ __forceinline__ void fma4(float4& a, const float4& w, float s) {
    a.x = fmaf(s, w.x, a.x); a.y = fmaf(s, w.y, a.y);
    a.z = fmaf(s, w.z, a.z); a.w = fmaf(s, w.w, a.w);
}

template<int K, bool BIAS, bool RELU, bool STATS, bool ROWSCALE, bool BNIN, bool DUAL>
__global__ __launch_bounds__(256) void gemm_k(
    const float* __restrict__ in, const float* __restrict__ W, const float* __restrict__ Wb,
    const float* __restrict__ bias, const float* __restrict__ bias2,
    float* __restrict__ out, float* __restrict__ out2, int rows,
    float* __restrict__ gstats, float* __restrict__ gstats2,
    const float* __restrict__ attn, const float* __restrict__ noise,
    const float* __restrict__ bnstats, const float* __restrict__ gamma,
    const float* __restrict__ beta)
{
    constexpr int RPT = (K == 128) ? 2 : 4;   // rows per thread
    constexpr int TR  = 16 * RPT;             // tile rows (32 or 64)
    constexpr int KP  = K + 4;                // float4-aligned rows, <=2-way bank alias
    constexpr int SS  = DUAL ? 256 : 128;
    __shared__ float sW[K * 64];
    __shared__ float sWb[DUAL ? K * 64 : 4];
    __shared__ float sIn[TR * KP];
    __shared__ float sStat[STATS ? SS : 4];
    __shared__ float sA[BNIN ? 64 : 4];
    __shared__ float sD[BNIN ? 64 : 4];

    const int tid = threadIdx.x;
    for (int i = tid; i < K * 16; i += 256) ((float4*)sW)[i] = ((const float4*)W)[i];
    if (DUAL)
        for (int i = tid; i < K * 16; i += 256) ((float4*)sWb)[i] = ((const float4*)Wb)[i];
    if (BNIN && tid < 64) {
        float m   = bnstats[tid] * (1.f / NN);
        float v   = bnstats[64 + tid] * (1.f / NN) - m * m;
        float a   = rsqrtf(v + 1e-5f) * gamma[tid];
        sA[tid] = a;
        sD[tid] = beta[tid] - m * a;
    }

    int rg = (tid >> 4) * RPT;
    int c0 = (tid & 15) << 2;
    float4 bb  = make_float4(0.f, 0.f, 0.f, 0.f);
    float4 bb2 = make_float4(0.f, 0.f, 0.f, 0.f);
    if (BIAS) bb = *(const float4*)&bias[c0];
    if (BIAS && DUAL) bb2 = *(const float4*)&bias2[c0];

    for (int tile = blockIdx.x * TR; tile < rows; tile += gridDim.x * TR) {
        __syncthreads();  // covers W/BN staging on first iter + sIn reuse afterwards
        int nrows = min(TR, rows - tile);
        const float4* ig = (const float4*)(in + tile * K);
        const float4* ng = ROWSCALE ? (const float4*)(noise + tile * K) : nullptr;
        for (int i = tid; i < nrows * (K / 4); i += 256) {
            int rr = i / (K / 4), kk = (i - rr * (K / 4)) * 4;
            float4 t = ig[i];
            if (BNIN) {
                t.x = fmaf(sA[kk + 0], t.x, sD[kk + 0]);
                t.y = fmaf(sA[kk + 1], t.y, sD[kk + 1]);
                t.z = fmaf(sA[kk + 2], t.z, sD[kk + 2]);
                t.w = fmaf(sA[kk + 3], t.w, sD[kk + 3]);
            }
            if (ROWSCALE) {
                float4 nv = ng[i];
                float at = attn[tile + rr];
                t.x = fmaf(at, t.x, nv.x); t.y = fmaf(at, t.y, nv.y);
                t.z = fmaf(at, t.z, nv.z); t.w = fmaf(at, t.w, nv.w);
            }
            *(float4*)&sIn[rr * KP + kk] = t;
        }
        __syncthreads();

        float4 acc[RPT];
        float4 acc2[DUAL ? RPT : 1];
#pragma unroll
        for (int j = 0; j < RPT; ++j) acc[j] = bb;
        if (DUAL) {
#pragma unroll
            for (int j = 0; j < RPT; ++j) acc2[j] = bb2;
        }
#pragma unroll 2
        for (int k4 = 0; k4 < K / 4; ++k4) {
            float4 av[RPT];
#pragma unroll
            for (int j = 0; j < RPT; ++j)
                av[j] = *(const float4*)&sIn[(rg + j) * KP + k4 * 4];
            const float* wp = &sW[k4 * 4 * 64 + c0];
            float4 w0 = *(const float4*)(wp);
            float4 w1 = *(const float4*)(wp + 64);
            float4 w2 = *(const float4*)(wp + 128);
            float4 w3 = *(const float4*)(wp + 192);
#pragma unroll
            for (int j = 0; j < RPT; ++j) {
                fma4(acc[j], w0, av[j].x); fma4(acc[j], w1, av[j].y);
                fma4(acc[j], w2, av[j].z); fma4(acc[j], w3, av[j].w);
            }
            if (DUAL) {
                const float* wq = &sWb[k4 * 4 * 64 + c0];
                float4 u0 = *(const float4*)(wq);
                float4 u1 = *(const float4*)(wq + 64);
                float4 u2 = *(const float4*)(wq + 128);
                float4 u3 = *(const float4*)(wq + 192);
#pragma unroll
                for (int j = 0; j < RPT; ++j) {
                    fma4(acc2[j], u0, av[j].x); fma4(acc2[j], u1, av[j].y);
                    fma4(acc2[j], u2, av[j].z); fma4(acc2[j], u3, av[j].w);
                }
            }
        }
        if (RELU) {
#pragma unroll
            for (int j = 0; j < RPT; ++j) {
                acc[j].x = fmaxf(acc[j].x, 0.f); acc[j].y = fmaxf(acc[j].y, 0.f);
                acc[j].z = fmaxf(acc[j].z, 0.f); acc[j].w = fmaxf(acc[j].w, 0.f);
                if (DUAL) {
                    acc2[j].x = fmaxf(acc2[j].x, 0.f); acc2[j].y = fmaxf(acc2[j].y, 0.f);
                    acc2[j].z = fmaxf(acc2[j].z, 0.f); acc2[j].w = fmaxf(acc2[j].w, 0.f);
                }
            }
        }
#pragma unroll
        for (int j = 0; j < RPT; ++j) {
            int r = rg + j;
            if (r < nrows) {
                *(float4*)&out[(tile + r) * 64 + c0] = acc[j];
                if (DUAL) *(float4*)&out2[(tile + r) * 64 + c0] = acc2[j];
            }
        }
        if (STATS) {
            if (tid < SS) sStat[tid] = 0.f;
            __syncthreads();
            float sx = 0, sy = 0, sz = 0, sw = 0, qx = 0, qy = 0, qz = 0, qw = 0;
            float sx2 = 0, sy2 = 0, sz2 = 0, sw2 = 0, qx2 = 0, qy2 = 0, qz2 = 0, qw2 = 0;
#pragma unroll
            for (int j = 0; j < RPT; ++j) {
                if (rg + j < nrows) {
                    sx += acc[j].x; sy += acc[j].y; sz += acc[j].z; sw += acc[j].w;
                    qx += acc[j].x * acc[j].x; qy += acc[j].y * acc[j].y;
                    qz += acc[j].z * acc[j].z; qw += acc[j].w * acc[j].w;
                    if (DUAL) {
                        sx2 += acc2[j].x; sy2 += acc2[j].y; sz2 += acc2[j].z; sw2 += acc2[j].w;
                        qx2 += acc2[j].x * acc2[j].x; qy2 += acc2[j].y * acc2[j].y;
                        qz2 += acc2[j].z * acc2[j].z; qw2 += acc2[j].w * acc2[j].w;
                    }
                }
            }
            atomicAdd(&sStat[c0 + 0], sx); atomicAdd(&sStat[c0 + 1], sy);
            atomicAdd(&sStat[c0 + 2], sz); atomicAdd(&sStat[c0 + 3], sw);
            atomicAdd(&sStat[64 + c0 + 0], qx); atomicAdd(&sStat[64 + c0 + 1], qy);
            atomicAdd(&sStat[64 + c0 + 2], qz); atomicAdd(&sStat[64 + c0 + 3], qw);
            if (DUAL) {
                atomicAdd(&sStat[128 + c0 + 0], sx2); atomicAdd(&sStat[128 + c0 + 1], sy2);
                atomicAdd(&sStat[128 + c0 + 2], sz2); atomicAdd(&sStat[128 + c0 + 3], sw2);
                atomicAdd(&sStat[192 + c0 + 0], qx2); atomicAdd(&sStat[192 + c0 + 1], qy2);
                atomicAdd(&sStat[192 + c0 + 2], qz2); atomicAdd(&sStat[192 + c0 + 3], qw2);
            }
            __syncthreads();
            if (tid < 128) atomicAdd(&gstats[tid], sStat[tid]);
            if (DUAL && tid >= 128) atomicAdd(&gstats2[tid - 128], sStat[tid]);
        }
    }
}

// ---------------- batchnorm apply ----------------

__global__ void bn_apply_k(const float* __restrict__ in, float* __restrict__ out, int rows,
                           const float* __restrict__ stats, const float* __restrict__ gamma,
                           const float* __restrict__ beta) {
    int n = rows * 64;
    float invr = 1.f / (float)rows;
    for (int i = blockIdx.x * blockDim.x + threadIdx.x; i < n; i += gridDim.x * blockDim.x) {
        int c = i & 63;
        float m   = stats[c] * invr;
        float var = stats[64 + c] * invr - m * m;
        out[i] = (in[i] - m) * rsqrtf(var + 1e-5f) * gamma[c] + beta[c];
    }
}

// ---------------- segment boundaries (batch is sorted) ----------------

__global__ void seg_bounds_k(const int* __restrict__ batch, int* __restrict__ segstart) {
    int g = blockIdx.x * blockDim.x + threadIdx.x;
    if (g > GG) return;
    int lo = 0, hi = NN;
    while (lo < hi) {
        int mid = (lo + hi) >> 1;
        if (batch[mid] < g) lo = mid + 1; else hi = mid;
    }
    segstart[g] = lo;
}

// ---------------- mean pooling with fused BN affine: slots = a*mean(z)+d ----------------

__global__ __launch_bounds__(256) void graph_mean_bn_k(const float* __restrict__ z,
                                                       const int* __restrict__ segst,
                                                       const float* __restrict__ stats,
                                                       const float* __restrict__ gamma,
                                                       const float* __restrict__ beta,
                                                       float* __restrict__ slots) {
    int g = blockIdx.x, tid = threadIdx.x, w = tid >> 6, lane = tid & 63;
    int s0 = segst[g], s1 = segst[g + 1];
    float acc = 0.f;
    for (int n = s0 + w; n < s1; n += 4) acc += z[n * 64 + lane];
    __shared__ float red[256];
    red[tid] = acc;
    __syncthreads();
    if (tid < 64) {
        float m   = stats[tid] * (1.f / NN);
        float var = stats[64 + tid] * (1.f / NN) - m * m;
        float a   = rsqrtf(var + 1e-5f) * gamma[tid];
        float d   = beta[tid] - m * a;
        float mean = (red[tid] + red[64 + tid] + red[128 + tid] + red[192 + tid])
                   / (float)max(s1 - s0, 1);
        slots[g * 64 + tid] = a * mean + d;
    }
}

// ---------------- fused attention iteration: q -> logits -> softmax -> updates -> GRU ----------------

__global__ __launch_bounds__(256) void attn_iter_k(
    const float* __restrict__ kbuf, const float* __restrict__ vbuf,
    float* __restrict__ slots, const int* __restrict__ segst,
    const float* __restrict__ Wq,
    const float* __restrict__ Wih, const float* __restrict__ Whh,
    const float* __restrict__ bih, const float* __restrict__ bhh,
    float* __restrict__ attn, int final_iter)
{
    int g = blockIdx.x, tid = threadIdx.x, w = tid >> 6, lane = tid & 63;
    __shared__ float ssl[64], sq[64], sred[256], supd[64], ssum[4];
    __shared__ float sgi[192], sgh[192];
    __shared__ float smax, sstot;

    if (tid < 64) ssl[tid] = slots[g * 64 + tid];
    __syncthreads();
    {
        float p = 0.f;
#pragma unroll
        for (int kk = 0; kk < 16; ++kk) p += ssl[w * 16 + kk] * Wq[(w * 16 + kk) * 64 + lane];
        sred[tid] = p;
    }
    __syncthreads();
    if (tid < 64) sq[tid] = sred[tid] + sred[64 + tid] + sred[128 + tid] + sred[192 + tid];
    __syncthreads();

    int s0 = segst[g], s1 = segst[g + 1];
    float qd = sq[lane];

    float m = -INFINITY;
    for (int n = s0 + w; n < s1; n += 4) {
        float p = kbuf[n * 64 + lane] * qd;
        p += __shfl_xor(p, 1);  p += __shfl_xor(p, 2);  p += __shfl_xor(p, 4);
        p += __shfl_xor(p, 8);  p += __shfl_xor(p, 16); p += __shfl_xor(p, 32);
        p *= 0.125f;  // 1/sqrt(64)
        if (lane == 0) attn[n] = p;
        m = fmaxf(m, p);
    }
    if (lane == 0) sred[w] = m;
    __syncthreads();
    if (tid == 0) smax = fmaxf(fmaxf(sred[0], sred[1]), fmaxf(sred[2], sred[3]));
    __syncthreads();
    m = smax;

    float s = 0.f, upd = 0.f;
    for (int n = s0 + w; n < s1; n += 4) {
        float e = expf(attn[n] - m);
        if (lane == 0) attn[n] = e;
        s += e;
        upd += e * vbuf[n * 64 + lane];
    }
    sred[tid] = upd;
    if (lane == 0) ssum[w] = s;
    __syncthreads();
    if (tid < 64) {
        float st = ssum[0] + ssum[1] + ssum[2] + ssum[3] + 1e-9f;
        if (tid == 0) sstot = st;
        supd[tid] = (sred[tid] + sred[64 + tid] + sred[128 + tid] + sred[192 + tid]) / st;
    }
    __syncthreads();

    if (final_iter) {
        float inv = 1.f / sstot;
        for (int n = s0 + tid; n < s1; n += 256) attn[n] *= inv;
    }

    if (tid < 192) {
        float a = bih[tid], b = bhh[tid];
        const float* wi = &Wih[tid * 64];
        const float* wh = &Whh[tid * 64];
#pragma unroll 8
        for (int j = 0; j < 64; ++j) { a += supd[j] * wi[j]; b += ssl[j] * wh[j]; }
        sgi[tid] = a; sgh[tid] = b;
    }
    __syncthreads();
    if (tid < 64) {
        float r  = 1.f / (1.f + expf(-(sgi[tid] + sgh[tid])));
        float z  = 1.f / (1.f + expf(-(sgi[64 + tid] + sgh[64 + tid])));
        float nn = tanhf(sgi[128 + tid] + r * sgh[128 + tid]);
        slots[g * 64 + tid] = (1.f - z) * nn + z * ssl[tid];
    }
}

// ---------------- host side ----------------

extern "C" void kernel_launch(void* const* d_in, const int* in_sizes, int n_in,
                              void* d_out, int out_size, void* d_ws, size_t ws_size,
                              hipStream_t stream) {
    (void)in_sizes; (void)n_in; (void)out_size; (void)ws_size;

    const float* x      = (const float*)d_in[0];
    const int*   ei     = (const int*)d_in[1];
    const int*   srcI   = ei;
    const int*   dstI   = ei + EE;
    const int*   batch  = (const int*)d_in[2];
    const float* noise  = (const float*)d_in[3];
    const float* W1_0   = (const float*)d_in[4];
    const float* b1_0   = (const float*)d_in[5];
    const float* W2_0   = (const float*)d_in[6];
    const float* b2_0   = (const float*)d_in[7];
    const float* W1_r   = (const float*)d_in[8];
    const float* b1_r   = (const float*)d_in[9];
    const float* W2_r   = (const float*)d_in[10];
    const float* b2_r   = (const float*)d_in[11];
    const float* bn_g   = (const float*)d_in[12];
    const float* bn_b   = (const float*)d_in[13];
    const float* Wq     = (const float*)d_in[14];
    const float* Wk     = (const float*)d_in[15];
    const float* Wv     = (const float*)d_in[16];
    const float* Wih    = (const float*)d_in[17];
    const float* Whh    = (const float*)d_in[18];
    const float* bih    = (const float*)d_in[19];
    const float* bhh    = (const float*)d_in[20];
    const float* nmW    = (const float*)d_in[21];
    const float* nmb    = (const float*)d_in[22];
    const float* nlW    = (const float*)d_in[23];
    const float* nlb    = (const float*)d_in[24];
    const float* gmW    = (const float*)d_in[25];
    const float* gmb    = (const float*)d_in[26];
    const float* glW    = (const float*)d_in[27];
    const float* glb    = (const float*)d_in[28];
    const float* pj_g   = (const float*)d_in[29];
    const float* pj_b   = (const float*)d_in[30];

    float* ws      = (float*)d_ws;
    float* B0      = ws;                       // NN*DD
    float* B1      = B0 + NN * DD;             // NN*DD
    float* B2      = B1 + NN * DD;             // NN*DD
    float* slots   = B2 + NN * DD;             // GG*DD
    float* gpre1   = slots + GG * DD;          // GG*DD
    float* gpre2   = gpre1 + GG * DD;          // GG*DD
    float* attn    = gpre2 + GG * DD;          // NN
    float* stats   = attn + NN;                // 7*128
    int*   segst   = (int*)(stats + 7 * 128);  // GG+1
    int*   rowst   = segst + GG + 1;           // NN+1
    int*   cursor  = rowst + NN + 1;           // NN
    int*   bsum    = cursor + NN;              // 64
    int*   bofs    = bsum + 64;                // 64
    int*   csr_src = bofs + 64;                // EE

    float* s0 = stats, *s1 = stats + 128, *s2 = stats + 256, *s3 = stats + 384,
         * s4 = stats + 512, *s5 = stats + 640, *s6 = stats + 768;

    float* outp = (float*)d_out;
    float* out_nmu = outp;
    float* out_nlv = outp + NN * DD;
    float* out_gmu = outp + 2 * NN * DD;
    float* out_glv = outp + 2 * NN * DD + GG * DD;

    constexpr int NB = (NN + 1023) / 1024;       // 49 scan chunks
    constexpr int GE2 = (EE / 2 + 255) / 256;    // 1563 (2 edges/thread)
    const float* np = nullptr;
    float* zp = nullptr;

#define GK(...) <<<__VA_ARGS__, 0, stream>>>
    // ---------- init + CSR build + segments ----------
    zero_all_k GK((NN + 255) / 256, 256)(cursor, stats);
    hist_k GK(GE2, 256)(dstI, cursor);
    scanA_k GK(NB, 1024)(cursor, rowst, bsum);
    scanB_k GK(1, 64)(bsum, bofs, NB);
    scanC_k GK((NN + 255) / 256, 256)(rowst, bofs, cursor);
    fill_k GK(GE2, 256)(srcI, dstI, cursor, csr_src);
    seg_bounds_k GK(3, 256)(batch, segst);

    // ---------- GIN layer 0 (GEMM-first: gather on 64-wide) ----------
    gemm_k<128,false,false,false,false,false,false> GK(1563, 256)
        (x, W1_0, np, np, np, B0, zp, NN, zp, zp, np, np, np, np, np);
    gin_agg_br_k GK(3125, 256)(B0, rowst, csr_src, b1_0, B1);
    gemm_k<64,true,true,true,false,false,false> GK(782, 256)
        (B1, W2_0, np, b2_0, np, B2, zp, NN, s0, zp, np, np, np, np, np);

    // ---------- GIN layer 1 (BN0 affine fused into staging) ----------
    gemm_k<64,false,false,false,false,true,false> GK(782, 256)
        (B2, W1_r, np, np, np, B0, zp, NN, zp, zp, np, np, s0, bn_g + 0, bn_b + 0);
    gin_agg_br_k GK(3125, 256)(B0, rowst, csr_src, b1_r, B1);
    gemm_k<64,true,true,true,false,false,false> GK(782, 256)
        (B1, W2_r, np, b2_r, np, B2, zp, NN, s1, zp, np, np, np, np, np);

    // ---------- GIN layer 2 ----------
    gemm_k<64,false,false,false,false,true,false> GK(782, 256)
        (B2, W1_r + DD * DD, np, np, np, B0, zp, NN, zp, zp, np, np, s1, bn_g + 64, bn_b + 64);
    gin_agg_br_k GK(3125, 256)(B0, rowst, csr_src, b1_r + DD, B1);
    gemm_k<64,true,true,true,false,false,false> GK(782, 256)
        (B1, W2_r + DD * DD, np, b2_r + DD, np, B2, zp, NN, s2, zp, np, np, np, np, np);
    // B2 = z2 (pre-BN); final BN affine (s2, bn[2]) fused into all consumers.

    // ---------- summary maker ----------
    graph_mean_bn_k GK(GG, 256)(B2, segst, s2, bn_g + 128, bn_b + 128, slots);
    gemm_k<64,false,false,false,false,true,true> GK(782, 256)   // k,v in one pass
        (B2, Wk, Wv, np, np, B0, B1, NN, zp, zp, np, np, s2, bn_g + 128, bn_b + 128);
    attn_iter_k GK(GG, 256)(B0, B1, slots, segst, Wq, Wih, Whh, bih, bhh, attn, 0);
    attn_iter_k GK(GG, 256)(B0, B1, slots, segst, Wq, Wih, Whh, bih, bhh, attn, 1);

    // ---------- node heads (noisy = attn*BN(z)+noise fused into staging; DUAL) ----------
    gemm_k<64,true,true,true,true,true,true> GK(782, 256)
        (B2, nmW, nlW, nmb, nlb, B0, B1, NN, s3, s4, attn, noise, s2, bn_g + 128, bn_b + 128);
    bn_apply_k GK(2048, 256)(B0, out_nmu, NN, s3, pj_g + 0, pj_b + 0);
    bn_apply_k GK(2048, 256)(B1, out_nlv, NN, s4, pj_g + 64, pj_b + 64);

    // ---------- graph heads ----------
    gemm_k<64,true,true,true,false,false,true> GK(8, 256)
        (slots, gmW, glW, gmb, glb, gpre1, gpre2, GG, s5, s6, np, np, np, np, np);
    bn_apply_k GK(128, 256)(gpre1, out_gmu, GG, s5, pj_g + 128, pj_b + 128);
    bn_apply_k GK(128, 256)(gpre2, out_glv, GG, s6, pj_g + 192, pj_b + 192);
#undef GK
}